// Round 4
// baseline (181.093 us; speedup 1.0000x reference)
//
#include <hip/hip_runtime.h>
#include <stdint.h>

#define BB 4
#define NN 2048
#define FIN 256
#define FOUT 128
#define NH 4
#define NEG_SLOPE 0.2f

typedef short bf16x8 __attribute__((ext_vector_type(8)));
typedef unsigned short u16x8 __attribute__((ext_vector_type(8)));
typedef float f32x4 __attribute__((ext_vector_type(4)));
typedef unsigned long long u64;

__device__ inline float b2f(unsigned short u) {
    union { unsigned int i; float f; } x; x.i = ((unsigned int)u) << 16; return x.f;
}
__device__ inline unsigned short f2b(float f) {   // fp32 -> bf16 RNE
    union { float f; unsigned int i; } x; x.f = f;
    unsigned int r = x.i + 0x7fffu + ((x.i >> 16) & 1u);
    return (unsigned short)(r >> 16);
}
union F16U { unsigned short u; _Float16 h; };
__device__ inline float f16lo(unsigned int v) { F16U x; x.u = (unsigned short)(v & 0xffffu); return (float)x.h; }
__device__ inline float f16hi(unsigned int v) { F16U x; x.u = (unsigned short)(v >> 16); return (float)x.h; }
__device__ inline unsigned int packf16(float a, float b) {
    F16U x, y; x.h = (_Float16)a; y.h = (_Float16)b;
    return (unsigned int)x.u | ((unsigned int)y.u << 16);
}

// ---------------------------------------------------------------------------
// kcvtW: split W fp32 -> bf16 hi/lo pair (for 3-product split MFMA in k1)
// ---------------------------------------------------------------------------
__global__ __launch_bounds__(256) void kcvt_w(const float* __restrict__ Ww,
                                              unsigned short* __restrict__ Whi,
                                              unsigned short* __restrict__ Wlo) {
    int idx = blockIdx.x * 256 + threadIdx.x;   // 32768 elems
    float v = Ww[idx];
    unsigned short hb = f2b(v);
    Whi[idx] = hb;
    Wlo[idx] = f2b(v - b2f(hb));
}

// ---------------------------------------------------------------------------
// K1 (MFMA): Wh[16 rows][128 o] = h_tile @ W^T + b, split-bf16 (hi*hi+hi*lo+lo*hi).
// Epilogue: WhT bf16 [b][o][n]; exp tables:
//   ELpair[b*4+h][i] = (exp(eL), exp(0.2 eL)) fp32x2
//   ERpk  [b][j][h]  = packf16(exp(eR), exp(0.2 eR))   (k2b layout)
//   ERpk2 [b*4+h][j] = same packed u32                  (kpack layout)
// ---------------------------------------------------------------------------
__global__ __launch_bounds__(256) void k1_wh(
    const float* __restrict__ h, const unsigned short* __restrict__ Whi,
    const unsigned short* __restrict__ Wlo, const float* __restrict__ Wb,
    const float* __restrict__ attw, unsigned short* __restrict__ WhT,
    float2* __restrict__ ELpair, unsigned int* __restrict__ ERpk,
    unsigned int* __restrict__ ERpk2) {
    __shared__ unsigned short Ahi[16][264];   // stride 264: 16B-aligned rows
    __shared__ unsigned short Alo[16][264];
    __shared__ float whs[16][132];
    int t = threadIdx.x;
    int b = blockIdx.x >> 7;
    int n0 = (blockIdx.x & 127) * 16;
    // stage h tile, split into hi/lo bf16
    {
        int r = t >> 4, c = (t & 15) * 16;
        const float* hp = h + ((size_t)(b * NN + n0 + r)) * FIN + c;
        u16x8 hi0, hi1, lo0, lo1;
        #pragma unroll
        for (int q = 0; q < 4; ++q) {
            float4 v = *(const float4*)(hp + q * 4);
            float vv[4] = {v.x, v.y, v.z, v.w};
            #pragma unroll
            for (int e = 0; e < 4; ++e) {
                int idx = q * 4 + e;
                unsigned short hb = f2b(vv[e]);
                unsigned short lb = f2b(vv[e] - b2f(hb));
                if (idx < 8) { hi0[idx] = (short)hb; lo0[idx] = (short)lb; }
                else         { hi1[idx - 8] = (short)hb; lo1[idx - 8] = (short)lb; }
            }
        }
        *(u16x8*)&Ahi[r][c] = *(u16x8*)&hi0;
        *(u16x8*)&Ahi[r][c + 8] = *(u16x8*)&hi1;
        *(u16x8*)&Alo[r][c] = *(u16x8*)&lo0;
        *(u16x8*)&Alo[r][c + 8] = *(u16x8*)&lo1;
    }
    __syncthreads();
    int lane = t & 63, wv = t >> 6;
    int m = lane & 15, quad = lane >> 4;
    int o0 = wv * 32;
    f32x4 acc0 = {0.f, 0.f, 0.f, 0.f}, acc1 = {0.f, 0.f, 0.f, 0.f};
    const unsigned short* wh0 = Whi + (size_t)(o0 + m) * FIN;
    const unsigned short* wl0 = Wlo + (size_t)(o0 + m) * FIN;
    const unsigned short* wh1 = Whi + (size_t)(o0 + 16 + m) * FIN;
    const unsigned short* wl1 = Wlo + (size_t)(o0 + 16 + m) * FIN;
    #pragma unroll
    for (int ks = 0; ks < 8; ++ks) {
        int ko = ks * 32 + quad * 8;
        bf16x8 ahi = *(bf16x8*)&Ahi[m][ko];
        bf16x8 alo = *(bf16x8*)&Alo[m][ko];
        bf16x8 bh0 = *(const bf16x8*)(wh0 + ko);
        bf16x8 bl0 = *(const bf16x8*)(wl0 + ko);
        bf16x8 bh1 = *(const bf16x8*)(wh1 + ko);
        bf16x8 bl1 = *(const bf16x8*)(wl1 + ko);
        acc0 = __builtin_amdgcn_mfma_f32_16x16x32_bf16(ahi, bh0, acc0, 0, 0, 0);
        acc0 = __builtin_amdgcn_mfma_f32_16x16x32_bf16(ahi, bl0, acc0, 0, 0, 0);
        acc0 = __builtin_amdgcn_mfma_f32_16x16x32_bf16(alo, bh0, acc0, 0, 0, 0);
        acc1 = __builtin_amdgcn_mfma_f32_16x16x32_bf16(ahi, bh1, acc1, 0, 0, 0);
        acc1 = __builtin_amdgcn_mfma_f32_16x16x32_bf16(ahi, bl1, acc1, 0, 0, 0);
        acc1 = __builtin_amdgcn_mfma_f32_16x16x32_bf16(alo, bh1, acc1, 0, 0, 0);
    }
    float bias0 = Wb[o0 + m], bias1 = Wb[o0 + 16 + m];
    #pragma unroll
    for (int reg = 0; reg < 4; ++reg) {
        int row = quad * 4 + reg;
        whs[row][o0 + m] = acc0[reg] + bias0;
        whs[row][o0 + 16 + m] = acc1[reg] + bias1;
    }
    __syncthreads();
    // WhT writer: 2 threads per o, 8 n each
    {
        int o = t >> 1, half = t & 1;
        u16x8 v8;
        #pragma unroll
        for (int r = 0; r < 8; ++r) v8[r] = (short)f2b(whs[half * 8 + r][o]);
        *(u16x8*)(WhT + (size_t)(b * FOUT + o) * NN + n0 + half * 8) = v8;
    }
    // e-dots + exp tables: out = (i, h, side), 2 threads split the 128-dot
    {
        int outi = t >> 1, half = t & 1;
        int i = outi >> 3, d = outi & 7, hh = d & 3, side = d >> 2;
        const float* arow = attw + hh * (2 * FOUT) + side * FOUT + half * 64;
        float s = 0.f;
        #pragma unroll 8
        for (int k = 0; k < 64; ++k) s = fmaf(whs[i][half * 64 + k], arow[k], s);
        s += __shfl_xor(s, 1);
        if (half == 0) {
            float p = __expf(s), n = __expf(NEG_SLOPE * s);
            int bh = b * NH + hh;
            if (side == 0) {
                ELpair[(size_t)bh * NN + n0 + i] = make_float2(p, n);
            } else {
                unsigned int pk = packf16(p, n);
                ERpk[((size_t)b * NN + n0 + i) * NH + hh] = pk;
                ERpk2[(size_t)bh * NN + n0 + i] = pk;
            }
        }
    }
}

// ---------------------------------------------------------------------------
// kpack_fused: per adj row i: bitmask + s[b,h,i] = sum_j bit*max(ELp*ERp, ELn*ERn)
// -> inv[b,h,i] = 1/(4s) (0 if empty)
// ---------------------------------------------------------------------------
__global__ __launch_bounds__(256) void kpack_fused(
    const int* __restrict__ adj, const float2* __restrict__ ELpair,
    const unsigned int* __restrict__ ERpk2, u64* __restrict__ mask,
    float* __restrict__ inv) {
    __shared__ float red[16][4];
    int i = blockIdx.x;
    int t = threadIdx.x, lane = t & 63, wv = t >> 6;
    int nz[8];
    #pragma unroll
    for (int k = 0; k < 8; ++k) {
        int a = adj[(size_t)i * NN + k * 256 + t];
        nz[k] = (a != 0);
        u64 bal = __ballot(nz[k] != 0);
        if (lane == 0) mask[i * 32 + k * 4 + wv] = bal;
    }
    float s[16];
    #pragma unroll
    for (int bh = 0; bh < 16; ++bh) {
        float2 el = ELpair[(size_t)bh * NN + i];    // broadcast
        float acc = 0.f;
        #pragma unroll
        for (int k = 0; k < 8; ++k) {
            unsigned int er = ERpk2[(size_t)bh * NN + k * 256 + t];
            float p = fmaxf(el.x * f16lo(er), el.y * f16hi(er));
            acc += nz[k] ? p : 0.f;
        }
        s[bh] = acc;
    }
    #pragma unroll
    for (int bh = 0; bh < 16; ++bh) {
        float v = s[bh];
        #pragma unroll
        for (int off = 32; off; off >>= 1) v += __shfl_xor(v, off);
        if (lane == 0) red[bh][wv] = v;
        s[bh] = v;
    }
    __syncthreads();
    if (t < 16) {
        float tot = red[t][0] + red[t][1] + red[t][2] + red[t][3];
        inv[(size_t)t * NN + i] = (tot > 0.f) ? 1.f / (4.f * tot) : 0.f;
    }
}

// ---------------------------------------------------------------------------
// K2b: P[b,i,o] += sum_{j in half} w[i,j] * Wh[b,j,o]  (MFMA, atomicAdd partials)
//   w[i,j] = bit * sum_h inv_h * max(ELp_h ERp_h, ELn_h ERn_h)
// grid (128 itiles, B, 2 jhalf), 256 thr. j chunk 256 per jt, 4 jt.
// ---------------------------------------------------------------------------
__global__ __launch_bounds__(256) void k2b_mfma(
    const unsigned short* __restrict__ WhT, const float2* __restrict__ ELpair,
    const unsigned int* __restrict__ ERpk, const float* __restrict__ inv,
    const u64* __restrict__ mask, float* __restrict__ P) {
    __shared__ unsigned short wt[16][264];
    int t = threadIdx.x;
    int b = blockIdx.y, i0 = blockIdx.x * 16, jhalf = blockIdx.z;
    int lane = t & 63, wv = t >> 6;
    int il = lane & 15, g = (lane >> 4) & 3;
    int m = il, quad = lane >> 4;
    // prologue: inv-scaled EL pairs for all 4 heads (lane row = il)
    float elp[NH], eln[NH];
    #pragma unroll
    for (int hh = 0; hh < NH; ++hh) {
        int bh = b * NH + hh;
        float2 e2 = ELpair[(size_t)bh * NN + i0 + il];
        float iv = inv[(size_t)bh * NN + i0 + il];
        elp[hh] = e2.x * iv;
        eln[hh] = e2.y * iv;
    }
    int o0 = wv * 32;
    const unsigned short* bp0 = WhT + (size_t)(b * FOUT + o0 + m) * NN;
    const unsigned short* bp1 = WhT + (size_t)(b * FOUT + o0 + 16 + m) * NN;
    f32x4 acc0 = {0.f, 0.f, 0.f, 0.f}, acc1 = {0.f, 0.f, 0.f, 0.f};

    for (int jt = 0; jt < 4; ++jt) {
        int jabs0 = jhalf * 1024 + jt * 256;
        __syncthreads();   // wt consumed by previous MFMA phase
        // w-gen: wave wv covers local j [wv*64, wv*64+64); lane (il, g)
        u64 mwv = mask[(size_t)(i0 + il) * 32 + jhalf * 16 + jt * 4 + wv];
        const uint4* erb = (const uint4*)(ERpk + ((size_t)b * NN + jabs0 + wv * 64) * NH);
        #pragma unroll 4
        for (int it2 = 0; it2 < 16; ++it2) {
            int jsub = it2 * 4 + g;            // within wave's 64
            uint4 er4 = erb[jsub];
            float p = fmaxf(elp[0] * f16lo(er4.x), eln[0] * f16hi(er4.x));
            p += fmaxf(elp[1] * f16lo(er4.y), eln[1] * f16hi(er4.y));
            p += fmaxf(elp[2] * f16lo(er4.z), eln[2] * f16hi(er4.z));
            p += fmaxf(elp[3] * f16lo(er4.w), eln[3] * f16hi(er4.w));
            int bit = (int)((mwv >> jsub) & 1ull);
            wt[il][wv * 64 + jsub] = bit ? f2b(p) : 0;
        }
        __syncthreads();
        // MFMA phase
        #pragma unroll
        for (int ks = 0; ks < 8; ++ks) {
            int ko = ks * 32 + quad * 8;
            bf16x8 a = *(bf16x8*)&wt[m][ko];
            bf16x8 b0 = *(const bf16x8*)(bp0 + jabs0 + ko);
            bf16x8 b1 = *(const bf16x8*)(bp1 + jabs0 + ko);
            acc0 = __builtin_amdgcn_mfma_f32_16x16x32_bf16(a, b0, acc0, 0, 0, 0);
            acc1 = __builtin_amdgcn_mfma_f32_16x16x32_bf16(a, b1, acc1, 0, 0, 0);
        }
    }
    float* pb = P + ((size_t)b * NN + i0) * FOUT;
    #pragma unroll
    for (int reg = 0; reg < 4; ++reg) {
        int row = quad * 4 + reg;
        atomicAdd(&pb[(size_t)row * FOUT + o0 + m], acc0[reg]);
        atomicAdd(&pb[(size_t)row * FOUT + o0 + 16 + m], acc1[reg]);
    }
}

// ---------------------------------------------------------------------------
// K3: out = relu(P)
// ---------------------------------------------------------------------------
__global__ __launch_bounds__(256) void k3_relu(const float* __restrict__ P,
                                               float* __restrict__ out) {
    int idx = blockIdx.x * 256 + threadIdx.x;
    float4 v = ((const float4*)P)[idx];
    v.x = fmaxf(v.x, 0.f); v.y = fmaxf(v.y, 0.f);
    v.z = fmaxf(v.z, 0.f); v.w = fmaxf(v.w, 0.f);
    ((float4*)out)[idx] = v;
}

extern "C" void kernel_launch(void* const* d_in, const int* in_sizes, int n_in,
                              void* d_out, int out_size, void* d_ws, size_t ws_size,
                              hipStream_t stream) {
    const float* h    = (const float*)d_in[0];
    const int* adj    = (const int*)d_in[1];
    const float* Ww   = (const float*)d_in[2];
    const float* Wb   = (const float*)d_in[3];
    const float* attw = (const float*)d_in[4];
    float* out = (float*)d_out;
    char* ws = (char*)d_ws;
    // workspace layout (7.25 MB)
    unsigned short* Whi = (unsigned short*)(ws);                 // 64 KB
    unsigned short* Wlo = (unsigned short*)(ws + 65536);         // 64 KB
    unsigned short* WhT = (unsigned short*)(ws + 131072);        // 2 MB [b][o][n] bf16
    float2*       ELpair = (float2*)(ws + 2228224);              // 256 KB [bh][i]
    unsigned int* ERpk   = (unsigned int*)(ws + 2490368);        // 128 KB [b][j][h] f16pk
    unsigned int* ERpk2  = (unsigned int*)(ws + 2621440);        // 128 KB [bh][j] f16pk
    float*        invB   = (float*)(ws + 2752512);               // 128 KB [bh][i]
    u64*          mask   = (u64*)(ws + 2883584);                 // 512 KB
    float*        P      = (float*)(ws + 3407872);               // 4 MB fp32

    hipMemsetAsync(P, 0, 4194304, stream);
    kcvt_w<<<dim3(128), dim3(256), 0, stream>>>(Ww, Whi, Wlo);
    k1_wh<<<dim3(BB * NN / 16), dim3(256), 0, stream>>>(h, Whi, Wlo, Wb, attw,
                                                        WhT, ELpair, ERpk, ERpk2);
    kpack_fused<<<dim3(NN), dim3(256), 0, stream>>>(adj, ELpair, ERpk2, mask, invB);
    k2b_mfma<<<dim3(NN / 16, BB, 2), dim3(256), 0, stream>>>(WhT, ELpair, ERpk,
                                                             invB, mask, P);
    k3_relu<<<dim3(1024), dim3(256), 0, stream>>>(P, out);
}

// Round 5
// 174.279 us; speedup vs baseline: 1.0391x; 1.0391x over previous
//
#include <hip/hip_runtime.h>
#include <stdint.h>

#define BB 4
#define NN 2048
#define FIN 256
#define FOUT 128
#define NH 4
#define NEG_SLOPE 0.2f

typedef short bf16x8 __attribute__((ext_vector_type(8)));
typedef unsigned short u16x8 __attribute__((ext_vector_type(8)));
typedef float f32x4 __attribute__((ext_vector_type(4)));
typedef unsigned long long u64;

__device__ inline float b2f(unsigned short u) {
    union { unsigned int i; float f; } x; x.i = ((unsigned int)u) << 16; return x.f;
}
__device__ inline unsigned short f2b(float f) {   // fp32 -> bf16 RNE
    union { float f; unsigned int i; } x; x.f = f;
    unsigned int r = x.i + 0x7fffu + ((x.i >> 16) & 1u);
    return (unsigned short)(r >> 16);
}
__device__ inline unsigned short f2b_fast(float f) {  // round-half-up (f >= 0 here)
    union { float f; unsigned int i; } x; x.f = f;
    return (unsigned short)((x.i + 0x8000u) >> 16);
}
union F16U { unsigned short u; _Float16 h; };
__device__ inline float f16lo(unsigned int v) { F16U x; x.u = (unsigned short)(v & 0xffffu); return (float)x.h; }
__device__ inline float f16hi(unsigned int v) { F16U x; x.u = (unsigned short)(v >> 16); return (float)x.h; }
__device__ inline unsigned int packf16(float a, float b) {
    F16U x, y; x.h = (_Float16)a; y.h = (_Float16)b;
    return (unsigned int)x.u | ((unsigned int)y.u << 16);
}

// ---------------------------------------------------------------------------
// kcvtW: split W fp32 -> bf16 hi/lo pair (for 3-product split MFMA in k1)
// ---------------------------------------------------------------------------
__global__ __launch_bounds__(256) void kcvt_w(const float* __restrict__ Ww,
                                              unsigned short* __restrict__ Whi,
                                              unsigned short* __restrict__ Wlo) {
    int idx = blockIdx.x * 256 + threadIdx.x;   // 32768 elems
    float v = Ww[idx];
    unsigned short hb = f2b(v);
    Whi[idx] = hb;
    Wlo[idx] = f2b(v - b2f(hb));
}

// ---------------------------------------------------------------------------
// K1 (MFMA): Wh[16 rows][128 o] = h_tile @ W^T + b, split-bf16 (hh+hl+lh).
// Epilogue: WhT bf16 [b][o][n]; exp tables:
//   ELpair[b*4+h][i] = (exp(eL), exp(0.2 eL)) fp32x2       (kpack input)
//   ERpk  [b][j][h]  = packf16(exp(eR), exp(0.2 eR))       (k2b layout)
//   ERpk2 [b*4+h][j] = same packed u32                      (kpack layout)
// ---------------------------------------------------------------------------
__global__ __launch_bounds__(256) void k1_wh(
    const float* __restrict__ h, const unsigned short* __restrict__ Whi,
    const unsigned short* __restrict__ Wlo, const float* __restrict__ Wb,
    const float* __restrict__ attw, unsigned short* __restrict__ WhT,
    float2* __restrict__ ELpair, unsigned int* __restrict__ ERpk,
    unsigned int* __restrict__ ERpk2) {
    __shared__ unsigned short Ahi[16][264];
    __shared__ unsigned short Alo[16][264];
    __shared__ float whs[16][132];
    int t = threadIdx.x;
    int b = blockIdx.x >> 7;
    int n0 = (blockIdx.x & 127) * 16;
    {
        int r = t >> 4, c = (t & 15) * 16;
        const float* hp = h + ((size_t)(b * NN + n0 + r)) * FIN + c;
        u16x8 hi0, hi1, lo0, lo1;
        #pragma unroll
        for (int q = 0; q < 4; ++q) {
            float4 v = *(const float4*)(hp + q * 4);
            float vv[4] = {v.x, v.y, v.z, v.w};
            #pragma unroll
            for (int e = 0; e < 4; ++e) {
                int idx = q * 4 + e;
                unsigned short hb = f2b(vv[e]);
                unsigned short lb = f2b(vv[e] - b2f(hb));
                if (idx < 8) { hi0[idx] = (short)hb; lo0[idx] = (short)lb; }
                else         { hi1[idx - 8] = (short)hb; lo1[idx - 8] = (short)lb; }
            }
        }
        *(u16x8*)&Ahi[r][c] = *(u16x8*)&hi0;
        *(u16x8*)&Ahi[r][c + 8] = *(u16x8*)&hi1;
        *(u16x8*)&Alo[r][c] = *(u16x8*)&lo0;
        *(u16x8*)&Alo[r][c + 8] = *(u16x8*)&lo1;
    }
    __syncthreads();
    int lane = t & 63, wv = t >> 6;
    int m = lane & 15, quad = lane >> 4;
    int o0 = wv * 32;
    f32x4 acc0 = {0.f, 0.f, 0.f, 0.f}, acc1 = {0.f, 0.f, 0.f, 0.f};
    const unsigned short* wh0 = Whi + (size_t)(o0 + m) * FIN;
    const unsigned short* wl0 = Wlo + (size_t)(o0 + m) * FIN;
    const unsigned short* wh1 = Whi + (size_t)(o0 + 16 + m) * FIN;
    const unsigned short* wl1 = Wlo + (size_t)(o0 + 16 + m) * FIN;
    #pragma unroll
    for (int ks = 0; ks < 8; ++ks) {
        int ko = ks * 32 + quad * 8;
        bf16x8 ahi = *(bf16x8*)&Ahi[m][ko];
        bf16x8 alo = *(bf16x8*)&Alo[m][ko];
        bf16x8 bh0 = *(const bf16x8*)(wh0 + ko);
        bf16x8 bl0 = *(const bf16x8*)(wl0 + ko);
        bf16x8 bh1 = *(const bf16x8*)(wh1 + ko);
        bf16x8 bl1 = *(const bf16x8*)(wl1 + ko);
        acc0 = __builtin_amdgcn_mfma_f32_16x16x32_bf16(ahi, bh0, acc0, 0, 0, 0);
        acc0 = __builtin_amdgcn_mfma_f32_16x16x32_bf16(ahi, bl0, acc0, 0, 0, 0);
        acc0 = __builtin_amdgcn_mfma_f32_16x16x32_bf16(alo, bh0, acc0, 0, 0, 0);
        acc1 = __builtin_amdgcn_mfma_f32_16x16x32_bf16(ahi, bh1, acc1, 0, 0, 0);
        acc1 = __builtin_amdgcn_mfma_f32_16x16x32_bf16(ahi, bl1, acc1, 0, 0, 0);
        acc1 = __builtin_amdgcn_mfma_f32_16x16x32_bf16(alo, bh1, acc1, 0, 0, 0);
    }
    float bias0 = Wb[o0 + m], bias1 = Wb[o0 + 16 + m];
    #pragma unroll
    for (int reg = 0; reg < 4; ++reg) {
        int row = quad * 4 + reg;
        whs[row][o0 + m] = acc0[reg] + bias0;
        whs[row][o0 + 16 + m] = acc1[reg] + bias1;
    }
    __syncthreads();
    {   // WhT writer: 2 threads per o, 8 n each
        int o = t >> 1, half = t & 1;
        u16x8 v8;
        #pragma unroll
        for (int r = 0; r < 8; ++r) v8[r] = (short)f2b(whs[half * 8 + r][o]);
        *(u16x8*)(WhT + (size_t)(b * FOUT + o) * NN + n0 + half * 8) = v8;
    }
    {   // e-dots + exp tables
        int outi = t >> 1, half = t & 1;
        int i = outi >> 3, d = outi & 7, hh = d & 3, side = d >> 2;
        const float* arow = attw + hh * (2 * FOUT) + side * FOUT + half * 64;
        float s = 0.f;
        #pragma unroll 8
        for (int k = 0; k < 64; ++k) s = fmaf(whs[i][half * 64 + k], arow[k], s);
        s += __shfl_xor(s, 1);
        if (half == 0) {
            float p = __expf(s), n = __expf(NEG_SLOPE * s);
            int bh = b * NH + hh;
            if (side == 0) {
                ELpair[(size_t)bh * NN + n0 + i] = make_float2(p, n);
            } else {
                unsigned int pk = packf16(p, n);
                ERpk[((size_t)b * NN + n0 + i) * NH + hh] = pk;
                ERpk2[(size_t)bh * NN + n0 + i] = pk;
            }
        }
    }
}

// ---------------------------------------------------------------------------
// kpack_fused: per adj row i: bitmask; s[b,h,i] = sum_j bit*max(ELp*ERp,ELn*ERn);
// ELSC[b][i][h][2] = ELpair * (1/(4s))  (0 if empty row)
// ---------------------------------------------------------------------------
__global__ __launch_bounds__(256) void kpack_fused(
    const int* __restrict__ adj, const float2* __restrict__ ELpair,
    const unsigned int* __restrict__ ERpk2, u64* __restrict__ mask,
    float* __restrict__ ELSC) {
    __shared__ float red[16][4];
    int i = blockIdx.x;
    int t = threadIdx.x, lane = t & 63, wv = t >> 6;
    int nz[8];
    #pragma unroll
    for (int k = 0; k < 8; ++k) {
        int a = adj[(size_t)i * NN + k * 256 + t];
        nz[k] = (a != 0);
        u64 bal = __ballot(nz[k] != 0);
        if (lane == 0) mask[i * 32 + k * 4 + wv] = bal;
    }
    float s[16];
    #pragma unroll
    for (int bh = 0; bh < 16; ++bh) {
        float2 el = ELpair[(size_t)bh * NN + i];    // uniform -> scalar load
        float acc = 0.f;
        #pragma unroll
        for (int k = 0; k < 8; ++k) {
            unsigned int er = ERpk2[(size_t)bh * NN + k * 256 + t];
            float p = fmaxf(el.x * f16lo(er), el.y * f16hi(er));
            acc += nz[k] ? p : 0.f;
        }
        s[bh] = acc;
    }
    #pragma unroll
    for (int bh = 0; bh < 16; ++bh) {
        float v = s[bh];
        #pragma unroll
        for (int off = 32; off; off >>= 1) v += __shfl_xor(v, off);
        if (lane == 0) red[bh][wv] = v;
    }
    __syncthreads();
    if (t < 16) {
        float tot = red[t][0] + red[t][1] + red[t][2] + red[t][3];
        float iv = (tot > 0.f) ? 1.f / (4.f * tot) : 0.f;
        float2 el = ELpair[(size_t)t * NN + i];
        int bb = t >> 2, hh = t & 3;
        float* dst = ELSC + ((size_t)bb * NN + i) * 8 + hh * 2;
        dst[0] = el.x * iv;
        dst[1] = el.y * iv;
    }
}

// ---------------------------------------------------------------------------
// K2b: out[b,i,o] = relu( sum_j w[i,j] * Wh[b,j,o] ), MFMA 16x16x32 bf16.
//   w[i,j] = bit(i,j) * sum_h max(ELSCp_h(i)*ERp_h(j), ELSCn_h(i)*ERn_h(j))
// Block = 256 thr (4 waves) per (i-tile 16, b). Each wave OWNS 4 rows for
// w-gen (constants in VGPRs, mask words via wave-uniform scalar loads,
// ER via coalesced uint4), then all waves MFMA over the 256-j chunk.
// ---------------------------------------------------------------------------
__global__ __launch_bounds__(256) void k2b_mfma(
    const unsigned short* __restrict__ WhT, const unsigned int* __restrict__ ERpk,
    const float* __restrict__ ELSC, const u64* __restrict__ mask,
    float* __restrict__ out) {
    __shared__ unsigned short wt[16][264];
    int t = threadIdx.x;
    int b = blockIdx.y, i0 = blockIdx.x * 16;
    int lane = t & 63, wv = t >> 6;
    int m = lane & 15, quad = lane >> 4;
    int r0 = wv * 4;
    // wave-row constants: 4 rows x 4 heads x (p,n) in VGPRs (uniform loads)
    float c_elp[4][4], c_eln[4][4];
    #pragma unroll
    for (int r = 0; r < 4; ++r) {
        const float4* ep = (const float4*)(ELSC + ((size_t)b * NN + i0 + r0 + r) * 8);
        float4 a0 = ep[0], a1 = ep[1];
        c_elp[r][0] = a0.x; c_eln[r][0] = a0.y;
        c_elp[r][1] = a0.z; c_eln[r][1] = a0.w;
        c_elp[r][2] = a1.x; c_eln[r][2] = a1.y;
        c_elp[r][3] = a1.z; c_eln[r][3] = a1.w;
    }
    int o0 = wv * 32;
    const unsigned short* bp0 = WhT + (size_t)(b * FOUT + o0 + m) * NN;
    const unsigned short* bp1 = WhT + (size_t)(b * FOUT + o0 + 16 + m) * NN;
    f32x4 acc0 = {0.f, 0.f, 0.f, 0.f}, acc1 = {0.f, 0.f, 0.f, 0.f};

    for (int jt = 0; jt < 8; ++jt) {
        int jabs0 = jt * 256;
        __syncthreads();   // wt consumed by previous MFMA phase
        #pragma unroll
        for (int q = 0; q < 4; ++q) {
            int jl = q * 64 + lane;
            uint4 er4 = *(const uint4*)(ERpk + ((size_t)b * NN + jabs0 + jl) * 4);
            float erp0 = f16lo(er4.x), ern0 = f16hi(er4.x);
            float erp1 = f16lo(er4.y), ern1 = f16hi(er4.y);
            float erp2 = f16lo(er4.z), ern2 = f16hi(er4.z);
            float erp3 = f16lo(er4.w), ern3 = f16hi(er4.w);
            #pragma unroll
            for (int r = 0; r < 4; ++r) {
                u64 mw = mask[(size_t)(i0 + r0 + r) * 32 + jt * 4 + q];  // uniform
                float p = fmaxf(c_elp[r][0] * erp0, c_eln[r][0] * ern0);
                p += fmaxf(c_elp[r][1] * erp1, c_eln[r][1] * ern1);
                p += fmaxf(c_elp[r][2] * erp2, c_eln[r][2] * ern2);
                p += fmaxf(c_elp[r][3] * erp3, c_eln[r][3] * ern3);
                wt[r0 + r][jl] = ((mw >> lane) & 1ull) ? f2b_fast(p) : 0;
            }
        }
        __syncthreads();
        #pragma unroll
        for (int ks = 0; ks < 8; ++ks) {
            int ko = ks * 32 + quad * 8;
            bf16x8 a = *(bf16x8*)&wt[m][ko];
            bf16x8 b0 = *(const bf16x8*)(bp0 + jabs0 + ko);
            bf16x8 b1 = *(const bf16x8*)(bp1 + jabs0 + ko);
            acc0 = __builtin_amdgcn_mfma_f32_16x16x32_bf16(a, b0, acc0, 0, 0, 0);
            acc1 = __builtin_amdgcn_mfma_f32_16x16x32_bf16(a, b1, acc1, 0, 0, 0);
        }
    }
    float* ob = out + ((size_t)b * NN + i0) * FOUT;
    #pragma unroll
    for (int reg = 0; reg < 4; ++reg) {
        int row = quad * 4 + reg;
        ob[(size_t)row * FOUT + o0 + m]      = fmaxf(acc0[reg], 0.f);
        ob[(size_t)row * FOUT + o0 + 16 + m] = fmaxf(acc1[reg], 0.f);
    }
}

extern "C" void kernel_launch(void* const* d_in, const int* in_sizes, int n_in,
                              void* d_out, int out_size, void* d_ws, size_t ws_size,
                              hipStream_t stream) {
    const float* h    = (const float*)d_in[0];
    const int* adj    = (const int*)d_in[1];
    const float* Ww   = (const float*)d_in[2];
    const float* Wb   = (const float*)d_in[3];
    const float* attw = (const float*)d_in[4];
    float* out = (float*)d_out;
    char* ws = (char*)d_ws;
    // workspace layout (3.4 MB)
    unsigned short* Whi = (unsigned short*)(ws);                 // 64 KB
    unsigned short* Wlo = (unsigned short*)(ws + 65536);         // 64 KB
    unsigned short* WhT = (unsigned short*)(ws + 131072);        // 2 MB [b][o][n] bf16
    float2*       ELpair = (float2*)(ws + 2228224);              // 256 KB [bh][i]
    unsigned int* ERpk   = (unsigned int*)(ws + 2490368);        // 128 KB [b][j][h] f16pk
    unsigned int* ERpk2  = (unsigned int*)(ws + 2621440);        // 128 KB [bh][j] f16pk
    float*        ELSC   = (float*)(ws + 2752512);               // 256 KB [b][i][h][2]
    u64*          mask   = (u64*)(ws + 3014656);                 // 512 KB

    kcvt_w<<<dim3(128), dim3(256), 0, stream>>>(Ww, Whi, Wlo);
    k1_wh<<<dim3(BB * NN / 16), dim3(256), 0, stream>>>(h, Whi, Wlo, Wb, attw,
                                                        WhT, ELpair, ERpk, ERpk2);
    kpack_fused<<<dim3(NN), dim3(256), 0, stream>>>(adj, ELpair, ERpk2, mask, ELSC);
    k2b_mfma<<<dim3(NN / 16, BB), dim3(256), 0, stream>>>(WhT, ERpk, ELSC, mask, out);
}

// Round 6
// 155.434 us; speedup vs baseline: 1.1651x; 1.1212x over previous
//
#include <hip/hip_runtime.h>
#include <stdint.h>

#define BB 4
#define NN 2048
#define FIN 256
#define FOUT 128
#define NH 4
#define NEG_SLOPE 0.2f

typedef short bf16x8 __attribute__((ext_vector_type(8)));
typedef unsigned short u16x8 __attribute__((ext_vector_type(8)));
typedef float f32x4 __attribute__((ext_vector_type(4)));
typedef unsigned long long u64;

__device__ inline float b2f(unsigned short u) {
    union { unsigned int i; float f; } x; x.i = ((unsigned int)u) << 16; return x.f;
}
__device__ inline unsigned short f2b(float f) {   // fp32 -> bf16 RNE
    union { float f; unsigned int i; } x; x.f = f;
    unsigned int r = x.i + 0x7fffu + ((x.i >> 16) & 1u);
    return (unsigned short)(r >> 16);
}
__device__ inline unsigned short f2b_fast(float f) {  // round-half-up (f >= 0 here)
    union { float f; unsigned int i; } x; x.f = f;
    return (unsigned short)((x.i + 0x8000u) >> 16);
}
union F16U { unsigned short u; _Float16 h; };
__device__ inline float f16lo(unsigned int v) { F16U x; x.u = (unsigned short)(v & 0xffffu); return (float)x.h; }
__device__ inline float f16hi(unsigned int v) { F16U x; x.u = (unsigned short)(v >> 16); return (float)x.h; }
__device__ inline unsigned int packf16(float a, float b) {
    F16U x, y; x.h = (_Float16)a; y.h = (_Float16)b;
    return (unsigned int)x.u | ((unsigned int)y.u << 16);
}

// ---------------------------------------------------------------------------
// kcvtW: split W fp32 -> bf16 hi/lo pair
// ---------------------------------------------------------------------------
__global__ __launch_bounds__(256) void kcvt_w(const float* __restrict__ Ww,
                                              unsigned short* __restrict__ Whi,
                                              unsigned short* __restrict__ Wlo) {
    int idx = blockIdx.x * 256 + threadIdx.x;   // 32768 elems
    float v = Ww[idx];
    unsigned short hb = f2b(v);
    Whi[idx] = hb;
    Wlo[idx] = f2b(v - b2f(hb));
}

// ---------------------------------------------------------------------------
// K1 (MFMA): Wh[16 rows][128 o] = h_tile @ W^T + b, split-bf16 (hh+hl+lh).
// Epilogue: WhT bf16 [b][o][n]; exp tables:
//   ELpair[b*4+h][i] = (exp(eL), exp(0.2 eL)) fp32x2       (kpack input)
//   ERpk  [b][j][h]  = packf16(exp(eR), exp(0.2 eR))       (k2b layout)
//   ERpk2 [b*4+h][j] = same packed u32                      (kpack layout)
// ---------------------------------------------------------------------------
__global__ __launch_bounds__(256) void k1_wh(
    const float* __restrict__ h, const unsigned short* __restrict__ Whi,
    const unsigned short* __restrict__ Wlo, const float* __restrict__ Wb,
    const float* __restrict__ attw, unsigned short* __restrict__ WhT,
    float2* __restrict__ ELpair, unsigned int* __restrict__ ERpk,
    unsigned int* __restrict__ ERpk2) {
    __shared__ unsigned short Ahi[16][264];
    __shared__ unsigned short Alo[16][264];
    __shared__ float whs[16][132];
    int t = threadIdx.x;
    int b = blockIdx.x >> 7;
    int n0 = (blockIdx.x & 127) * 16;
    {
        int r = t >> 4, c = (t & 15) * 16;
        const float* hp = h + ((size_t)(b * NN + n0 + r)) * FIN + c;
        u16x8 hi0, hi1, lo0, lo1;
        #pragma unroll
        for (int q = 0; q < 4; ++q) {
            float4 v = *(const float4*)(hp + q * 4);
            float vv[4] = {v.x, v.y, v.z, v.w};
            #pragma unroll
            for (int e = 0; e < 4; ++e) {
                int idx = q * 4 + e;
                unsigned short hb = f2b(vv[e]);
                unsigned short lb = f2b(vv[e] - b2f(hb));
                if (idx < 8) { hi0[idx] = (short)hb; lo0[idx] = (short)lb; }
                else         { hi1[idx - 8] = (short)hb; lo1[idx - 8] = (short)lb; }
            }
        }
        *(u16x8*)&Ahi[r][c] = *(u16x8*)&hi0;
        *(u16x8*)&Ahi[r][c + 8] = *(u16x8*)&hi1;
        *(u16x8*)&Alo[r][c] = *(u16x8*)&lo0;
        *(u16x8*)&Alo[r][c + 8] = *(u16x8*)&lo1;
    }
    __syncthreads();
    int lane = t & 63, wv = t >> 6;
    int m = lane & 15, quad = lane >> 4;
    int o0 = wv * 32;
    f32x4 acc0 = {0.f, 0.f, 0.f, 0.f}, acc1 = {0.f, 0.f, 0.f, 0.f};
    const unsigned short* wh0 = Whi + (size_t)(o0 + m) * FIN;
    const unsigned short* wl0 = Wlo + (size_t)(o0 + m) * FIN;
    const unsigned short* wh1 = Whi + (size_t)(o0 + 16 + m) * FIN;
    const unsigned short* wl1 = Wlo + (size_t)(o0 + 16 + m) * FIN;
    #pragma unroll
    for (int ks = 0; ks < 8; ++ks) {
        int ko = ks * 32 + quad * 8;
        bf16x8 ahi = *(bf16x8*)&Ahi[m][ko];
        bf16x8 alo = *(bf16x8*)&Alo[m][ko];
        bf16x8 bh0 = *(const bf16x8*)(wh0 + ko);
        bf16x8 bl0 = *(const bf16x8*)(wl0 + ko);
        bf16x8 bh1 = *(const bf16x8*)(wh1 + ko);
        bf16x8 bl1 = *(const bf16x8*)(wl1 + ko);
        acc0 = __builtin_amdgcn_mfma_f32_16x16x32_bf16(ahi, bh0, acc0, 0, 0, 0);
        acc0 = __builtin_amdgcn_mfma_f32_16x16x32_bf16(ahi, bl0, acc0, 0, 0, 0);
        acc0 = __builtin_amdgcn_mfma_f32_16x16x32_bf16(alo, bh0, acc0, 0, 0, 0);
        acc1 = __builtin_amdgcn_mfma_f32_16x16x32_bf16(ahi, bh1, acc1, 0, 0, 0);
        acc1 = __builtin_amdgcn_mfma_f32_16x16x32_bf16(ahi, bl1, acc1, 0, 0, 0);
        acc1 = __builtin_amdgcn_mfma_f32_16x16x32_bf16(alo, bh1, acc1, 0, 0, 0);
    }
    float bias0 = Wb[o0 + m], bias1 = Wb[o0 + 16 + m];
    #pragma unroll
    for (int reg = 0; reg < 4; ++reg) {
        int row = quad * 4 + reg;
        whs[row][o0 + m] = acc0[reg] + bias0;
        whs[row][o0 + 16 + m] = acc1[reg] + bias1;
    }
    __syncthreads();
    {   // WhT writer: 2 threads per o, 8 n each
        int o = t >> 1, half = t & 1;
        u16x8 v8;
        #pragma unroll
        for (int r = 0; r < 8; ++r) v8[r] = (short)f2b(whs[half * 8 + r][o]);
        *(u16x8*)(WhT + (size_t)(b * FOUT + o) * NN + n0 + half * 8) = v8;
    }
    {   // e-dots + exp tables
        int outi = t >> 1, half = t & 1;
        int i = outi >> 3, d = outi & 7, hh = d & 3, side = d >> 2;
        const float* arow = attw + hh * (2 * FOUT) + side * FOUT + half * 64;
        float s = 0.f;
        #pragma unroll 8
        for (int k = 0; k < 64; ++k) s = fmaf(whs[i][half * 64 + k], arow[k], s);
        s += __shfl_xor(s, 1);
        if (half == 0) {
            float p = __expf(s), n = __expf(NEG_SLOPE * s);
            int bh = b * NH + hh;
            if (side == 0) {
                ELpair[(size_t)bh * NN + n0 + i] = make_float2(p, n);
            } else {
                unsigned int pk = packf16(p, n);
                ERpk[((size_t)b * NN + n0 + i) * NH + hh] = pk;
                ERpk2[(size_t)bh * NN + n0 + i] = pk;
            }
        }
    }
}

// ---------------------------------------------------------------------------
// kpack_fused: per adj row i: bitmask; s[b,h,i] = sum_j bit*max(ELp*ERp,ELn*ERn);
// ELSC[b][i][h][2] = ELpair * (1/(4s))  (0 if empty row)
// ---------------------------------------------------------------------------
__global__ __launch_bounds__(256) void kpack_fused(
    const int* __restrict__ adj, const float2* __restrict__ ELpair,
    const unsigned int* __restrict__ ERpk2, u64* __restrict__ mask,
    float* __restrict__ ELSC) {
    __shared__ float red[16][4];
    int i = blockIdx.x;
    int t = threadIdx.x, lane = t & 63, wv = t >> 6;
    int nz[8];
    #pragma unroll
    for (int k = 0; k < 8; ++k) {
        int a = adj[(size_t)i * NN + k * 256 + t];
        nz[k] = (a != 0);
        u64 bal = __ballot(nz[k] != 0);
        if (lane == 0) mask[i * 32 + k * 4 + wv] = bal;
    }
    float s[16];
    #pragma unroll
    for (int bh = 0; bh < 16; ++bh) {
        float2 el = ELpair[(size_t)bh * NN + i];    // uniform -> scalar load
        float acc = 0.f;
        #pragma unroll
        for (int k = 0; k < 8; ++k) {
            unsigned int er = ERpk2[(size_t)bh * NN + k * 256 + t];
            float p = fmaxf(el.x * f16lo(er), el.y * f16hi(er));
            acc += nz[k] ? p : 0.f;
        }
        s[bh] = acc;
    }
    #pragma unroll
    for (int bh = 0; bh < 16; ++bh) {
        float v = s[bh];
        #pragma unroll
        for (int off = 32; off; off >>= 1) v += __shfl_xor(v, off);
        if (lane == 0) red[bh][wv] = v;
    }
    __syncthreads();
    if (t < 16) {
        float tot = red[t][0] + red[t][1] + red[t][2] + red[t][3];
        float iv = (tot > 0.f) ? 1.f / (4.f * tot) : 0.f;
        float2 el = ELpair[(size_t)t * NN + i];
        int bb = t >> 2, hh = t & 3;
        float* dst = ELSC + ((size_t)bb * NN + i) * 8 + hh * 2;
        dst[0] = el.x * iv;
        dst[1] = el.y * iv;
    }
}

// ---------------------------------------------------------------------------
// K2b: P[jhalf][b,i,o] = sum_{j in half} w[i,j] * Wh[b,j,o], MFMA 16x16x32.
// Block = 512 thr (8 waves), TI=64 i-rows, all 128 o, 1024 j (one half).
// Grid (32, 4, 2) = 256 blocks = 1/CU. Per chunk of 256 j:
//   [barrier] [B-prefetch to regs] [w-gen 64x256 -> LDS] [barrier] [MFMA].
// B traffic per CU = 256 KB (was 1 MB) — the R2-R5 invariant bottleneck.
// ---------------------------------------------------------------------------
__global__ __launch_bounds__(512, 2) void k2b_mfma(
    const unsigned short* __restrict__ WhT, const unsigned int* __restrict__ ERpk,
    const float* __restrict__ ELSC, const u64* __restrict__ mask,
    float* __restrict__ P) {
    __shared__ unsigned short wt[64][264];    // 33.8 KB bf16 w-tile
    __shared__ u64 mws[64][16];               // 8 KB: this j-half's mask words
    __shared__ float elsc_s[64][8];           // 2 KB
    int t = threadIdx.x;
    int b = blockIdx.y, i0 = blockIdx.x * 64, jhalf = blockIdx.z;
    int lane = t & 63, wv = t >> 6;
    int m = lane & 15, quad = lane >> 4;
    // stage ELSC rows i0..i0+63 (512 floats) and mask words (1024 u64)
    if (t < 128) {
        ((float4*)elsc_s)[t] = *(const float4*)(ELSC + ((size_t)b * NN + i0) * 8 + t * 4);
    }
    {
        int r = t >> 3, wp = (t & 7) * 2;
        *(ulonglong2*)&mws[r][wp] =
            *(const ulonglong2*)(mask + (size_t)(i0 + r) * 32 + jhalf * 16 + wp);
    }
    int r0 = wv * 8;                  // w-gen rows for this wave
    int o0 = wv * 16;                 // o-group for this wave
    const unsigned short* bp = WhT + (size_t)(b * FOUT + o0 + m) * NN + jhalf * 1024;
    f32x4 acc[4];
    #pragma unroll
    for (int k = 0; k < 4; ++k) acc[k] = (f32x4){0.f, 0.f, 0.f, 0.f};

    for (int ch = 0; ch < 4; ++ch) {
        int j0 = ch * 256;            // within this j-half
        __syncthreads();              // wt free (prev MFMA done); staging done (ch=0)
        // B prefetch: 8 x b128 into regs; latency hidden under w-gen VALU
        bf16x8 bfr[8];
        #pragma unroll
        for (int ks = 0; ks < 8; ++ks)
            bfr[ks] = *(const bf16x8*)(bp + j0 + ks * 32 + quad * 8);
        // cvt-pass: this lane's ER pairs for its 4 j columns
        float erp[4][4], ern[4][4];
        #pragma unroll
        for (int q = 0; q < 4; ++q) {
            int jg = jhalf * 1024 + j0 + q * 64 + lane;
            uint4 er4 = *(const uint4*)(ERpk + ((size_t)b * NN + jg) * 4);
            erp[q][0] = f16lo(er4.x); ern[q][0] = f16hi(er4.x);
            erp[q][1] = f16lo(er4.y); ern[q][1] = f16hi(er4.y);
            erp[q][2] = f16lo(er4.z); ern[q][2] = f16hi(er4.z);
            erp[q][3] = f16lo(er4.w); ern[q][3] = f16hi(er4.w);
        }
        // w-gen: 8 rows per wave
        #pragma unroll
        for (int r = 0; r < 8; ++r) {
            int ir = r0 + r;
            float4 c0 = *(float4*)&elsc_s[ir][0];   // broadcast
            float4 c1 = *(float4*)&elsc_s[ir][4];
            u64 mw0 = mws[ir][ch * 4 + 0];
            u64 mw1 = mws[ir][ch * 4 + 1];
            u64 mw2 = mws[ir][ch * 4 + 2];
            u64 mw3 = mws[ir][ch * 4 + 3];
            u64 mwq[4] = {mw0, mw1, mw2, mw3};
            #pragma unroll
            for (int q = 0; q < 4; ++q) {
                float p = fmaxf(c0.x * erp[q][0], c0.y * ern[q][0]);
                p += fmaxf(c0.z * erp[q][1], c0.w * ern[q][1]);
                p += fmaxf(c1.x * erp[q][2], c1.y * ern[q][2]);
                p += fmaxf(c1.z * erp[q][3], c1.w * ern[q][3]);
                wt[ir][q * 64 + lane] = ((mwq[q] >> lane) & 1ull) ? f2b_fast(p) : 0;
            }
        }
        __syncthreads();
        // MFMA: 4 i-subtiles x 8 ks; B shared across subtiles (in regs)
        #pragma unroll
        for (int isub = 0; isub < 4; ++isub) {
            #pragma unroll
            for (int ks = 0; ks < 8; ++ks) {
                bf16x8 a = *(bf16x8*)&wt[isub * 16 + m][ks * 32 + quad * 8];
                acc[isub] = __builtin_amdgcn_mfma_f32_16x16x32_bf16(a, bfr[ks], acc[isub], 0, 0, 0);
            }
        }
    }
    float* pb = P + (((size_t)jhalf * BB + b) * NN + i0) * FOUT;
    #pragma unroll
    for (int isub = 0; isub < 4; ++isub) {
        #pragma unroll
        for (int reg = 0; reg < 4; ++reg) {
            int row = isub * 16 + quad * 4 + reg;
            pb[(size_t)row * FOUT + o0 + m] = acc[isub][reg];
        }
    }
}

// ---------------------------------------------------------------------------
// K3: out = relu(P0 + P1)
// ---------------------------------------------------------------------------
__global__ __launch_bounds__(256) void k3_relu(const float* __restrict__ P,
                                               float* __restrict__ out) {
    int idx = blockIdx.x * 256 + threadIdx.x;   // float4 index over 4 MB
    float4 a = ((const float4*)P)[idx];
    float4 c = ((const float4*)P)[idx + (BB * NN * FOUT / 4)];
    a.x = fmaxf(a.x + c.x, 0.f); a.y = fmaxf(a.y + c.y, 0.f);
    a.z = fmaxf(a.z + c.z, 0.f); a.w = fmaxf(a.w + c.w, 0.f);
    ((float4*)out)[idx] = a;
}

extern "C" void kernel_launch(void* const* d_in, const int* in_sizes, int n_in,
                              void* d_out, int out_size, void* d_ws, size_t ws_size,
                              hipStream_t stream) {
    const float* h    = (const float*)d_in[0];
    const int* adj    = (const int*)d_in[1];
    const float* Ww   = (const float*)d_in[2];
    const float* Wb   = (const float*)d_in[3];
    const float* attw = (const float*)d_in[4];
    float* out = (float*)d_out;
    char* ws = (char*)d_ws;
    // workspace layout (11.4 MB)
    unsigned short* Whi = (unsigned short*)(ws);                 // 64 KB
    unsigned short* Wlo = (unsigned short*)(ws + 65536);         // 64 KB
    unsigned short* WhT = (unsigned short*)(ws + 131072);        // 2 MB [b][o][n] bf16
    float2*       ELpair = (float2*)(ws + 2228224);              // 256 KB [bh][i]
    unsigned int* ERpk   = (unsigned int*)(ws + 2490368);        // 128 KB [b][j][h] f16pk
    unsigned int* ERpk2  = (unsigned int*)(ws + 2621440);        // 128 KB [bh][j] f16pk
    float*        ELSC   = (float*)(ws + 2752512);               // 256 KB [b][i][h][2]
    u64*          mask   = (u64*)(ws + 3014656);                 // 512 KB
    float*        P      = (float*)(ws + 3538944);               // 2 x 4 MB partials

    kcvt_w<<<dim3(128), dim3(256), 0, stream>>>(Ww, Whi, Wlo);
    k1_wh<<<dim3(BB * NN / 16), dim3(256), 0, stream>>>(h, Whi, Wlo, Wb, attw,
                                                        WhT, ELpair, ERpk, ERpk2);
    kpack_fused<<<dim3(NN), dim3(256), 0, stream>>>(adj, ELpair, ERpk2, mask, ELSC);
    k2b_mfma<<<dim3(NN / 64, BB, 2), dim3(512), 0, stream>>>(WhT, ERpk, ELSC, mask, P);
    k3_relu<<<dim3(BB * NN * FOUT / 1024), dim3(256), 0, stream>>>(P, out);
}